// Round 15
// baseline (490.187 us; speedup 1.0000x reference)
//
#include <hip/hip_runtime.h>
#include <hip/hip_bf16.h>

#define BB  8
#define HIDC 128
#define INPC 320
#define CC  448
#define HH  64
#define WWI 128
#define HW  8192   // 64*128
#define NT_PER_B 512        // HW/16
#define KG  56              // CC/8
// frag-tiled dbuf: [b][nt][kg][ln(16)][kj(8)] bf16; elem off = ((b*512+nt)*56+kg)*128 + ln*8 + kj

using bf16   = __hip_bfloat16;
using bf16x8 = __attribute__((ext_vector_type(8))) __bf16;
using bf16x4 = __attribute__((ext_vector_type(4))) __bf16;
using bf16x2 = __attribute__((ext_vector_type(2))) __bf16;
using f32x4  = __attribute__((ext_vector_type(4))) float;
using f32x2  = __attribute__((ext_vector_type(2))) float;

__device__ __forceinline__ float b2f(bf16 v) { return __bfloat162float(v); }
__device__ __forceinline__ bf16  f2b(float v) { return __float2bfloat16(v); }

__device__ __forceinline__ void load2(const float* p, float& v0, float& v1) {
  f32x2 t = *reinterpret_cast<const f32x2*>(p);     // 8B-aligned (x0 even)
  v0 = t[0]; v1 = t[1];
}
__device__ __forceinline__ void load2(const bf16* p, float& v0, float& v1) {
  bf16x2 t = *reinterpret_cast<const bf16x2*>(p);   // 4B-aligned
  v0 = (float)t[0]; v1 = (float)t[1];
}

// ---------------- per-tensor symmetric int8 fake-quant ----------------
// scale = max(max|w|,1e-8)/127 ; q = clip(rint(w/scale),-128,127)
// dw gates: store q*scale as f32. pw gates: store q as bf16 INTEGER (exact),
// scale applied in the GEMM epilogue -> no bf16 rounding on weights.
__global__ __launch_bounds__(256) void quant_kernel(
    const float* wdz, const float* wpz, const float* wdr, const float* wpr,
    const float* wdq, const float* wpq, float* qwd, bf16* qwp, float* scales)
{
  const float* src = nullptr; int n = 0; float* df = nullptr; bf16* db = nullptr;
  int sidx = -1;
  switch (blockIdx.x) {
    case 0: src = wdz; n = CC * 9;    df = qwd;                 break;
    case 1: src = wpz; n = HIDC * CC; db = qwp;                 sidx = 0; break;
    case 2: src = wdr; n = CC * 9;    df = qwd + 4096;          break;
    case 3: src = wpr; n = HIDC * CC; db = qwp + HIDC * CC;     sidx = 1; break;
    case 4: src = wdq; n = CC * 9;    df = qwd + 8192;          break;
    case 5: src = wpq; n = HIDC * CC; db = qwp + 2 * HIDC * CC; sidx = 2; break;
  }
  __shared__ float red[256];
  int tid = threadIdx.x;
  float m = 0.f;
  for (int i = tid * 4; i < n; i += 1024) {          // n divisible by 4
    f32x4 v = *reinterpret_cast<const f32x4*>(src + i);
    m = fmaxf(m, fmaxf(fmaxf(fabsf(v[0]), fabsf(v[1])), fmaxf(fabsf(v[2]), fabsf(v[3]))));
  }
  red[tid] = m; __syncthreads();
  for (int s = 128; s > 0; s >>= 1) {
    if (tid < s) red[tid] = fmaxf(red[tid], red[tid + s]);
    __syncthreads();
  }
  float scale = fmaxf(red[0], 1e-8f) / 127.f;
  if (sidx >= 0 && tid == 0) scales[sidx] = scale;
  for (int i = tid * 4; i < n; i += 1024) {
    f32x4 v = *reinterpret_cast<const f32x4*>(src + i);
    float q[4];
#pragma unroll
    for (int j = 0; j < 4; j++) {
      float qq = rintf(v[j] / scale);                // RNE, matches jnp.round
      q[j] = fminf(fmaxf(qq, -128.f), 127.f);
    }
    if (df) {
      f32x4 o; o[0] = q[0] * scale; o[1] = q[1] * scale; o[2] = q[2] * scale; o[3] = q[3] * scale;
      *reinterpret_cast<f32x4*>(df + i) = o;
    } else {
      bf16x4 o; o[0] = (__bf16)q[0]; o[1] = (__bf16)q[1]; o[2] = (__bf16)q[2]; o[3] = (__bf16)q[3];
      *reinterpret_cast<bf16x4*>(db + i) = o;        // integers: exact in bf16
    }
  }
}

// ---------------- depthwise 3x3 SAME (f32 math), NCHW in -> frag-tiled bf16 --
// Thread: 2 adjacent x-pixels x 1 row x 8 channels; wave spans the 128-px row
// (x-halos via in-wave shuffles, SAME-pad zeros at edges); stores natively
// frag-tiled (32 B contiguous/thread, 256 B per 8-lane group).
// R14 VERDICT: 4 staging mechanisms (serial reg loads, LDS roundtrip, occu
// knob, async global_load_lds DMA) all land at ~2.4 TB/s / ~73us -> this
// access pattern is capped ~4 B/cy/CU (per-CU outstanding-miss limit), NOT
// per-wave latency. Simplest (R6) body restored; the lever is TRAFFIC.
// NG=3 (q-hoist): rhx channels 128..447 == hx channels 128..447, so the z/r
// pass ALSO computes the q-gate dwconv for cg>=16 from the SAME staged rows
// (zero extra reads, +42MB writes). dw2 then shrinks to 16 rh-cgroups
// (159MB -> 34MB traffic). Net -87MB ~ -35us at the pattern rate.
template <int NG, typename TH>
__global__ __launch_bounds__(256) void dwconv_kernel(
    const TH*    __restrict__ src_h,   // 128-ch tensor (h f32 or r*h bf16), NCHW
    const float* __restrict__ src_x,   // 320-ch tensor x, NCHW
    const float* __restrict__ w0, const float* __restrict__ b0,
    const float* __restrict__ w1, const float* __restrict__ b1,
    const float* __restrict__ w2, const float* __restrict__ b2,
    bf16* __restrict__ out0, bf16* __restrict__ out1, bf16* __restrict__ out2)
{
  int cg   = blockIdx.x;               // dw1: 0..55 ; dw2: 0..15
  int b    = blockIdx.z;               // 0..7
  int lane = threadIdx.x & 63;
  int w    = threadIdx.x >> 6;         // wave = row within quad
  int y    = blockIdx.y * 4 + w;       // block covers 4 rows
  int x0   = lane * 2;
  int c0   = cg * 8;
  bool in_h = (c0 < HIDC);
  bool g2   = (NG == 3) && (cg >= 16); // q-gate x-part (block-uniform)
  const TH*    baseh = src_h + ((size_t)b * HIDC + c0) * HW;
  const float* basex = src_x + ((size_t)b * INPC + (c0 - HIDC)) * HW;

  float a0[2][8], a1[2][8], a2[2][8];  // [px][ch]
#pragma unroll
  for (int i = 0; i < 8; i++) {
    int c = c0 + i;
    const TH*    ph = baseh + (size_t)i * HW;
    const float* pf = basex + (size_t)i * HW;
    float s00 = 0.f, s01 = 0.f, s10 = 0.f, s11 = 0.f, s20 = 0.f, s21 = 0.f;
#pragma unroll
    for (int dy = -1; dy <= 1; dy++) {
      int yy = y + dy;
      bool valid = (unsigned)yy < (unsigned)HH;
      int yc = valid ? yy : (yy < 0 ? 0 : HH - 1);   // clamped addr, zeroed below
      float v0, v1;
      if (in_h) load2(ph + yc * WWI + x0, v0, v1);
      else      load2(pf + yc * WWI + x0, v0, v1);
      if (!valid) { v0 = v1 = 0.f; }
      float vL = __shfl_up(v1, 1);
      if (lane == 0)  vL = 0.f;                      // x = -1 (SAME pad)
      float vR = __shfl_down(v0, 1);
      if (lane == 63) vR = 0.f;                      // x = 128 (SAME pad)
      int t = (dy + 1) * 3;
      float u0 = w0[c * 9 + t], u1 = w0[c * 9 + t + 1], u2 = w0[c * 9 + t + 2];
      s00 += vL * u0 + v0 * u1 + v1 * u2;            // out(x0)
      s01 += v0 * u0 + v1 * u1 + vR * u2;            // out(x0+1)
      if (NG >= 2) {
        float q0 = w1[c * 9 + t], q1 = w1[c * 9 + t + 1], q2 = w1[c * 9 + t + 2];
        s10 += vL * q0 + v0 * q1 + v1 * q2;
        s11 += v0 * q0 + v1 * q1 + vR * q2;
      }
      if (g2) {
        float r0 = w2[c * 9 + t], r1 = w2[c * 9 + t + 1], r2 = w2[c * 9 + t + 2];
        s20 += vL * r0 + v0 * r1 + v1 * r2;
        s21 += v0 * r0 + v1 * r1 + vR * r2;
      }
    }
    float bb0 = b0[c];
    a0[0][i] = s00 + bb0;
    a0[1][i] = s01 + bb0;
    if (NG >= 2) {
      float bb1 = b1[c];
      a1[0][i] = s10 + bb1;
      a1[1][i] = s11 + bb1;
    }
    if (g2) {
      float bb2 = b2[c];
      a2[0][i] = s20 + bb2;
      a2[1][i] = s21 + bb2;
    }
  }

  // store: px = x0+p ; elem off = ((b*512 + y*8 + px/16)*56 + cg)*128 + (px&15)*8
  // thread's two 16 B stores are contiguous (32 B); 8-lane groups cover 256 B.
#pragma unroll
  for (int p = 0; p < 2; p++) {
    int px = x0 + p;
    size_t off = (((size_t)b * NT_PER_B + y * 8 + (px >> 4)) * KG + cg) * 128 + (px & 15) * 8;
    bf16x8 v0;
#pragma unroll
    for (int i = 0; i < 8; i++) v0[i] = (__bf16)a0[p][i];
    *reinterpret_cast<bf16x8*>(out0 + off) = v0;
    if (NG >= 2) {
      bf16x8 v1;
#pragma unroll
      for (int i = 0; i < 8; i++) v1[i] = (__bf16)a1[p][i];
      *reinterpret_cast<bf16x8*>(out1 + off) = v1;
    }
    if (g2) {
      bf16x8 v2;
#pragma unroll
      for (int i = 0; i < 8; i++) v2[i] = (__bf16)a2[p][i];
      *reinterpret_cast<bf16x8*>(out2 + off) = v2;
    }
  }
}

// ---------------- pointwise 448->128 as MFMA GEMM + fused epilogue ----------
// NO LDS, NO BARRIERS. Frag-tiled dbuf means each wave's B-fragment load is a
// perfectly linear, fully-coalesced 1 KB global load. Waves fully independent.
// pre = (sum_k q_int[o][k]*d[n][k]) * scale + bias[o]
__device__ __forceinline__ void pw_gemm(const bf16* __restrict__ dbt,
                                        const bf16* __restrict__ wpm,  // wp + m0*CC
                                        int lane, f32x4 acc[2][4])
{
  int quad = lane >> 4;
  int lr   = lane & 15;
  const bf16* wp0 = wpm + (size_t)lr * CC + quad * 8;
  const bf16* bsrc = dbt + (size_t)lane * 8;
#pragma unroll
  for (int kk = 0; kk < 14; kk++) {
    bf16x8 a0 = *reinterpret_cast<const bf16x8*>(wp0 + kk * 32);
    bf16x8 a1 = *reinterpret_cast<const bf16x8*>(wp0 + 16 * CC + kk * 32);
#pragma unroll
    for (int nf = 0; nf < 4; nf++) {
      bf16x8 bfr = *reinterpret_cast<const bf16x8*>(bsrc + ((size_t)nf * KG + kk * 4) * 128);
      acc[0][nf] = __builtin_amdgcn_mfma_f32_16x16x32_bf16(a0, bfr, acc[0][nf], 0, 0, 0);
      acc[1][nf] = __builtin_amdgcn_mfma_f32_16x16x32_bf16(a1, bfr, acc[1][nf], 0, 0, 0);
    }
  }
}

// gates z (blockIdx.z==0) and r (blockIdx.z==1) fused in one launch
__global__ __launch_bounds__(256) void pw_zr_kernel(
    const bf16*  __restrict__ dz,     // frag-tiled dw output, gate z
    const bf16*  __restrict__ dr,     // frag-tiled dw output, gate r
    const bf16*  __restrict__ qwp,    // [2][128][448] int8-as-bf16 (z then r)
    const float* __restrict__ bpz, const float* __restrict__ bpr,
    const float* __restrict__ scales, // [z, r]
    const float* __restrict__ h,      // NCHW f32
    bf16* __restrict__ zout, bf16* __restrict__ rhout)
{
  int gate = blockIdx.z;
  const bf16*  dbuf = gate ? dr : dz;
  const bf16*  wp   = qwp + (size_t)gate * HIDC * CC;
  const float* bp   = gate ? bpr : bpz;
  float s = scales[gate];

  int b    = blockIdx.y;
  int n0   = blockIdx.x * 64;
  int nt0  = blockIdx.x * 4;
  int wave = threadIdx.x >> 6;
  int lane = threadIdx.x & 63;
  int quad = lane >> 4;
  int lr   = lane & 15;
  int m0   = wave * 32;              // each wave: 32 M-rows x 64 N
  f32x4 acc[2][4] = {};
  const bf16* dbt = dbuf + ((size_t)b * NT_PER_B + nt0) * (KG * 128);

  pw_gemm(dbt, wp + (size_t)m0 * CC, lane, acc);

  // epilogue: C/D layout col(N) = lane&15, row(M) = quad*4 + reg
#pragma unroll
  for (int mf = 0; mf < 2; mf++) {
#pragma unroll
    for (int r = 0; r < 4; r++) {
      int o = m0 + mf * 16 + quad * 4 + r;
      float bias = bp[o];
#pragma unroll
      for (int nf = 0; nf < 4; nf++) {
        int n = n0 + nf * 16 + lr;
        size_t idx = ((size_t)b * HIDC + o) * HW + n;
        float pre = acc[mf][nf][r] * s + bias;
        float sv  = 1.f / (1.f + expf(-pre));
        if (gate == 0) zout[idx]  = f2b(sv);
        else           rhout[idx] = f2b(sv * h[idx]);
      }
    }
  }
}

// gate q: q = tanh(pre); out = (1-z)*h + z*q
__global__ __launch_bounds__(256) void pw_q_kernel(
    const bf16*  __restrict__ dbuf,   // frag-tiled dw output, gate q
    const bf16*  __restrict__ wp,     // [128][448] int8-as-bf16
    const float* __restrict__ bp,
    const float* __restrict__ scale_p,
    const float* __restrict__ h,      // NCHW f32
    const bf16*  __restrict__ zin,    // bf16 z
    float* __restrict__ qout)
{
  int b    = blockIdx.y;
  int n0   = blockIdx.x * 64;
  int nt0  = blockIdx.x * 4;
  int wave = threadIdx.x >> 6;
  int lane = threadIdx.x & 63;
  int quad = lane >> 4;
  int lr   = lane & 15;
  int m0   = wave * 32;
  float s = *scale_p;
  f32x4 acc[2][4] = {};
  const bf16* dbt = dbuf + ((size_t)b * NT_PER_B + nt0) * (KG * 128);

  pw_gemm(dbt, wp + (size_t)m0 * CC, lane, acc);

#pragma unroll
  for (int mf = 0; mf < 2; mf++) {
#pragma unroll
    for (int r = 0; r < 4; r++) {
      int o = m0 + mf * 16 + quad * 4 + r;
      float bias = bp[o];
#pragma unroll
      for (int nf = 0; nf < 4; nf++) {
        int n = n0 + nf * 16 + lr;
        size_t idx = ((size_t)b * HIDC + o) * HW + n;
        float pre = acc[mf][nf][r] * s + bias;
        float qv = tanhf(pre);
        float zv = b2f(zin[idx]);
        float hv = h[idx];
        qout[idx] = (1.f - zv) * hv + zv * qv;
      }
    }
  }
}

extern "C" void kernel_launch(void* const* d_in, const int* in_sizes, int n_in,
                              void* d_out, int out_size, void* d_ws, size_t ws_size,
                              hipStream_t stream)
{
  const float* h   = (const float*)d_in[0];
  const float* x   = (const float*)d_in[1];
  const float* wdz = (const float*)d_in[2];
  const float* bdz = (const float*)d_in[3];
  const float* wpz = (const float*)d_in[4];
  const float* bpz = (const float*)d_in[5];
  const float* wdr = (const float*)d_in[6];
  const float* bdr = (const float*)d_in[7];
  const float* wpr = (const float*)d_in[8];
  const float* bpr = (const float*)d_in[9];
  const float* wdq = (const float*)d_in[10];
  const float* bdq = (const float*)d_in[11];
  const float* wpq = (const float*)d_in[12];
  const float* bpq = (const float*)d_in[13];

  char* ws = (char*)d_ws;
  float* qwd    = (float*)ws;                   // z@0 | r@4096 | q@8192 (f32)
  float* scales = qwd + 12288;                  // 3 floats
  bf16*  qwp    = (bf16*)(ws + 65536);          // 3 x 57344 bf16 (int8 values)
  const size_t DBUF_ELEMS = (size_t)BB * NT_PER_B * KG * 128;  // 29,360,128
  const size_t ZB_ELEMS   = (size_t)BB * HIDC * HW;            //  8,388,608
  bf16*  dz   = (bf16*)(ws + (1 << 20));                       // 58.7 MB
  bf16*  dr   = dz + DBUF_ELEMS;                               // 58.7 MB
  bf16*  zbuf = dr + DBUF_ELEMS;                               // 16.8 MB
  bf16*  rh   = zbuf + ZB_ELEMS;                               // 16.8 MB
  bf16*  dq   = rh + ZB_ELEMS;                                 // 58.7 MB (new path)
  const size_t NEED = (1 << 20) + (3 * DBUF_ELEMS + 2 * ZB_ELEMS) * sizeof(bf16);

  quant_kernel<<<6, 256, 0, stream>>>(wdz, wpz, wdr, wpr, wdq, wpq, qwd, qwp, scales);

  dim3 zrgrid(128, 8, 2);  // (64-wide n-tile, batch, gate z/r)
  dim3 pgrid(128, 8);      // (64-wide n-tile, batch)

  if (ws_size >= NEED) {
    // NEW PATH: q-gate x-channels hoisted into dw1 (NG=3, cg>=16); dw2 only
    // processes the 16 rh-cgroups. Saves 84MB of x re-read + shrinks dw2.
    dim3 dgrid(56, 16, 8);
    dwconv_kernel<3, float><<<dgrid, 256, 0, stream>>>(
        h, x, qwd, bdz, qwd + 4096, bdr, qwd + 8192, bdq, dz, dr, dq);

    pw_zr_kernel<<<zrgrid, 256, 0, stream>>>(dz, dr, qwp, bpz, bpr, scales, h, zbuf, rh);

    dim3 d2grid(16, 16, 8);   // rh channel-groups only (kg 0..15)
    dwconv_kernel<1, bf16><<<d2grid, 256, 0, stream>>>(
        rh, x, qwd + 8192, bdq, nullptr, nullptr, nullptr, nullptr,
        dq, nullptr, nullptr);

    pw_q_kernel<<<pgrid, 256, 0, stream>>>(dq, qwp + 2 * HIDC * CC, bpq, scales + 2,
                                           h, zbuf, (float*)d_out);
  } else {
    // FALLBACK (old 152MB layout): full dw2 on 56 cgroups, dq reuses dz.
    dim3 dgrid(56, 16, 8);
    dwconv_kernel<2, float><<<dgrid, 256, 0, stream>>>(
        h, x, qwd, bdz, qwd + 4096, bdr, nullptr, nullptr, dz, dr, nullptr);

    pw_zr_kernel<<<zrgrid, 256, 0, stream>>>(dz, dr, qwp, bpz, bpr, scales, h, zbuf, rh);

    dwconv_kernel<1, bf16><<<dgrid, 256, 0, stream>>>(
        rh, x, qwd + 8192, bdq, nullptr, nullptr, nullptr, nullptr,
        dz, nullptr, nullptr);

    pw_q_kernel<<<pgrid, 256, 0, stream>>>(dz, qwp + 2 * HIDC * CC, bpq, scales + 2,
                                           h, zbuf, (float*)d_out);
  }
}

// Round 16
// 376.488 us; speedup vs baseline: 1.3020x; 1.3020x over previous
//
#include <hip/hip_runtime.h>
#include <hip/hip_bf16.h>

#define BB  8
#define HIDC 128
#define INPC 320
#define CC  448
#define HH  64
#define WWI 128
#define HW  8192   // 64*128
#define NT_PER_B 512        // HW/16
#define KG  56              // CC/8
// frag-tiled dbuf: [b][nt][kg][ln(16)][kj(8)] bf16; elem off = ((b*512+nt)*56+kg)*128 + ln*8 + kj

using bf16   = __hip_bfloat16;
using bf16x8 = __attribute__((ext_vector_type(8))) __bf16;
using bf16x4 = __attribute__((ext_vector_type(4))) __bf16;
using bf16x2 = __attribute__((ext_vector_type(2))) __bf16;
using f32x4  = __attribute__((ext_vector_type(4))) float;
using f32x2  = __attribute__((ext_vector_type(2))) float;

__device__ __forceinline__ float b2f(bf16 v) { return __bfloat162float(v); }
__device__ __forceinline__ bf16  f2b(float v) { return __float2bfloat16(v); }

__device__ __forceinline__ void load2(const float* p, float& v0, float& v1) {
  f32x2 t = *reinterpret_cast<const f32x2*>(p);     // 8B-aligned (x0 even)
  v0 = t[0]; v1 = t[1];
}
__device__ __forceinline__ void load2(const bf16* p, float& v0, float& v1) {
  bf16x2 t = *reinterpret_cast<const bf16x2*>(p);   // 4B-aligned
  v0 = (float)t[0]; v1 = (float)t[1];
}

// ---------------- per-tensor symmetric int8 fake-quant ----------------
// scale = max(max|w|,1e-8)/127 ; q = clip(rint(w/scale),-128,127)
// dw gates: store q*scale as f32. pw gates: store q as bf16 INTEGER (exact),
// scale applied in the GEMM epilogue -> no bf16 rounding on weights.
__global__ __launch_bounds__(256) void quant_kernel(
    const float* wdz, const float* wpz, const float* wdr, const float* wpr,
    const float* wdq, const float* wpq, float* qwd, bf16* qwp, float* scales)
{
  const float* src = nullptr; int n = 0; float* df = nullptr; bf16* db = nullptr;
  int sidx = -1;
  switch (blockIdx.x) {
    case 0: src = wdz; n = CC * 9;    df = qwd;                 break;
    case 1: src = wpz; n = HIDC * CC; db = qwp;                 sidx = 0; break;
    case 2: src = wdr; n = CC * 9;    df = qwd + 4096;          break;
    case 3: src = wpr; n = HIDC * CC; db = qwp + HIDC * CC;     sidx = 1; break;
    case 4: src = wdq; n = CC * 9;    df = qwd + 8192;          break;
    case 5: src = wpq; n = HIDC * CC; db = qwp + 2 * HIDC * CC; sidx = 2; break;
  }
  __shared__ float red[256];
  int tid = threadIdx.x;
  float m = 0.f;
  for (int i = tid * 4; i < n; i += 1024) {          // n divisible by 4
    f32x4 v = *reinterpret_cast<const f32x4*>(src + i);
    m = fmaxf(m, fmaxf(fmaxf(fabsf(v[0]), fabsf(v[1])), fmaxf(fabsf(v[2]), fabsf(v[3]))));
  }
  red[tid] = m; __syncthreads();
  for (int s = 128; s > 0; s >>= 1) {
    if (tid < s) red[tid] = fmaxf(red[tid], red[tid + s]);
    __syncthreads();
  }
  float scale = fmaxf(red[0], 1e-8f) / 127.f;
  if (sidx >= 0 && tid == 0) scales[sidx] = scale;
  for (int i = tid * 4; i < n; i += 1024) {
    f32x4 v = *reinterpret_cast<const f32x4*>(src + i);
    float q[4];
#pragma unroll
    for (int j = 0; j < 4; j++) {
      float qq = rintf(v[j] / scale);                // RNE, matches jnp.round
      q[j] = fminf(fmaxf(qq, -128.f), 127.f);
    }
    if (df) {
      f32x4 o; o[0] = q[0] * scale; o[1] = q[1] * scale; o[2] = q[2] * scale; o[3] = q[3] * scale;
      *reinterpret_cast<f32x4*>(df + i) = o;
    } else {
      bf16x4 o; o[0] = (__bf16)q[0]; o[1] = (__bf16)q[1]; o[2] = (__bf16)q[2]; o[3] = (__bf16)q[3];
      *reinterpret_cast<bf16x4*>(db + i) = o;        // integers: exact in bf16
    }
  }
}

// ---------------- depthwise 3x3 SAME (f32 math), NCHW in -> frag-tiled bf16 --
// Thread: 2 adjacent x-pixels x 1 row x 8 channels; wave spans the 128-px row
// (x-halos via in-wave shuffles, SAME-pad zeros at edges); stores natively
// frag-tiled (32 B contiguous/thread, 256 B per 8-lane group).
// SESSION VERDICT (R4..R15): this body measured 379.5us total (best). All
// scheduling variants (sched_barrier fence R7, launch_bounds(256,2) R12,
// async global_load_lds DMA R14) and traffic restructurings (q-hoist R15,
// naive fusion R9) were neutral or regressed. The ~73us/dispatch at 2.4 TB/s
// with both pipes idle is this access pattern's empirical plateau.
template <int NG, typename TH>
__global__ __launch_bounds__(256) void dwconv_kernel(
    const TH*    __restrict__ src_h,   // 128-ch tensor (h f32 or r*h bf16), NCHW
    const float* __restrict__ src_x,   // 320-ch tensor x, NCHW
    const float* __restrict__ w0, const float* __restrict__ b0,
    const float* __restrict__ w1, const float* __restrict__ b1,
    bf16* __restrict__ out0, bf16* __restrict__ out1)   // frag-tiled
{
  int cg   = blockIdx.x;               // 0..55 (8 channels) == kg
  int b    = blockIdx.z;               // 0..7
  int lane = threadIdx.x & 63;
  int w    = threadIdx.x >> 6;         // wave = row within quad
  int y    = blockIdx.y * 4 + w;       // block covers 4 rows
  int x0   = lane * 2;
  int c0   = cg * 8;
  bool in_h = (c0 < HIDC);
  const TH*    baseh = src_h + ((size_t)b * HIDC + c0) * HW;
  const float* basex = src_x + ((size_t)b * INPC + (c0 - HIDC)) * HW;

  // row addresses (clamped); validity is wave-uniform
  int  yc[3]; bool vld[3];
#pragma unroll
  for (int d = 0; d < 3; d++) {
    int yy = y + d - 1;
    vld[d] = (unsigned)yy < (unsigned)HH;
    yc[d]  = vld[d] ? yy : (yy < 0 ? 0 : HH - 1);
  }

  // PHASE 1: issue all 24 loads back-to-back (static indices)
  float v[8][3][2];
#pragma unroll
  for (int i = 0; i < 8; i++) {
    const TH*    ph = baseh + (size_t)i * HW;
    const float* pf = basex + (size_t)i * HW;
#pragma unroll
    for (int d = 0; d < 3; d++) {
      if (in_h) load2(ph + yc[d] * WWI + x0, v[i][d][0], v[i][d][1]);
      else      load2(pf + yc[d] * WWI + x0, v[i][d][0], v[i][d][1]);
    }
  }

  // PHASE 2: shuffles + FMA per channel
  float a0[2][8], a1[2][8];            // [px][ch]
#pragma unroll
  for (int i = 0; i < 8; i++) {
    int c = c0 + i;
    float s00 = 0.f, s01 = 0.f, s10 = 0.f, s11 = 0.f;
#pragma unroll
    for (int d = 0; d < 3; d++) {
      float v0 = v[i][d][0], v1 = v[i][d][1];
      if (!vld[d]) { v0 = 0.f; v1 = 0.f; }           // uniform branch (SAME pad)
      float vL = __shfl_up(v1, 1);
      if (lane == 0)  vL = 0.f;                      // x = -1 (SAME pad)
      float vR = __shfl_down(v0, 1);
      if (lane == 63) vR = 0.f;                      // x = 128 (SAME pad)
      int t = d * 3;
      float u0 = w0[c * 9 + t], u1 = w0[c * 9 + t + 1], u2 = w0[c * 9 + t + 2];
      s00 += vL * u0 + v0 * u1 + v1 * u2;            // out(x0)
      s01 += v0 * u0 + v1 * u1 + vR * u2;            // out(x0+1)
      if (NG == 2) {
        float q0 = w1[c * 9 + t], q1 = w1[c * 9 + t + 1], q2 = w1[c * 9 + t + 2];
        s10 += vL * q0 + v0 * q1 + v1 * q2;
        s11 += v0 * q0 + v1 * q1 + vR * q2;
      }
    }
    float bb0 = b0[c];
    a0[0][i] = s00 + bb0;
    a0[1][i] = s01 + bb0;
    if (NG == 2) {
      float bb1 = b1[c];
      a1[0][i] = s10 + bb1;
      a1[1][i] = s11 + bb1;
    }
  }

  // store: px = x0+p ; elem off = ((b*512 + y*8 + px/16)*56 + cg)*128 + (px&15)*8
  // thread's two 16 B stores are contiguous (32 B); 8-lane groups cover 256 B.
#pragma unroll
  for (int p = 0; p < 2; p++) {
    int px = x0 + p;
    size_t off = (((size_t)b * NT_PER_B + y * 8 + (px >> 4)) * KG + cg) * 128 + (px & 15) * 8;
    bf16x8 v0;
#pragma unroll
    for (int i = 0; i < 8; i++) v0[i] = (__bf16)a0[p][i];
    *reinterpret_cast<bf16x8*>(out0 + off) = v0;
    if (NG == 2) {
      bf16x8 v1;
#pragma unroll
      for (int i = 0; i < 8; i++) v1[i] = (__bf16)a1[p][i];
      *reinterpret_cast<bf16x8*>(out1 + off) = v1;
    }
  }
}

// ---------------- pointwise 448->128 as MFMA GEMM + fused epilogue ----------
// NO LDS, NO BARRIERS. Frag-tiled dbuf means each wave's B-fragment load is a
// perfectly linear, fully-coalesced 1 KB global load. Waves fully independent.
// pre = (sum_k q_int[o][k]*d[n][k]) * scale + bias[o]
__device__ __forceinline__ void pw_gemm(const bf16* __restrict__ dbt,
                                        const bf16* __restrict__ wpm,  // wp + m0*CC
                                        int lane, f32x4 acc[2][4])
{
  int quad = lane >> 4;
  int lr   = lane & 15;
  const bf16* wp0 = wpm + (size_t)lr * CC + quad * 8;
  const bf16* bsrc = dbt + (size_t)lane * 8;
#pragma unroll
  for (int kk = 0; kk < 14; kk++) {
    bf16x8 a0 = *reinterpret_cast<const bf16x8*>(wp0 + kk * 32);
    bf16x8 a1 = *reinterpret_cast<const bf16x8*>(wp0 + 16 * CC + kk * 32);
#pragma unroll
    for (int nf = 0; nf < 4; nf++) {
      bf16x8 bfr = *reinterpret_cast<const bf16x8*>(bsrc + ((size_t)nf * KG + kk * 4) * 128);
      acc[0][nf] = __builtin_amdgcn_mfma_f32_16x16x32_bf16(a0, bfr, acc[0][nf], 0, 0, 0);
      acc[1][nf] = __builtin_amdgcn_mfma_f32_16x16x32_bf16(a1, bfr, acc[1][nf], 0, 0, 0);
    }
  }
}

// gates z (blockIdx.z==0) and r (blockIdx.z==1) fused in one launch
__global__ __launch_bounds__(256) void pw_zr_kernel(
    const bf16*  __restrict__ dz,     // frag-tiled dw output, gate z
    const bf16*  __restrict__ dr,     // frag-tiled dw output, gate r
    const bf16*  __restrict__ qwp,    // [2][128][448] int8-as-bf16 (z then r)
    const float* __restrict__ bpz, const float* __restrict__ bpr,
    const float* __restrict__ scales, // [z, r]
    const float* __restrict__ h,      // NCHW f32
    bf16* __restrict__ zout, bf16* __restrict__ rhout)
{
  int gate = blockIdx.z;
  const bf16*  dbuf = gate ? dr : dz;
  const bf16*  wp   = qwp + (size_t)gate * HIDC * CC;
  const float* bp   = gate ? bpr : bpz;
  float s = scales[gate];

  int b    = blockIdx.y;
  int n0   = blockIdx.x * 64;
  int nt0  = blockIdx.x * 4;
  int wave = threadIdx.x >> 6;
  int lane = threadIdx.x & 63;
  int quad = lane >> 4;
  int lr   = lane & 15;
  int m0   = wave * 32;              // each wave: 32 M-rows x 64 N
  f32x4 acc[2][4] = {};
  const bf16* dbt = dbuf + ((size_t)b * NT_PER_B + nt0) * (KG * 128);

  pw_gemm(dbt, wp + (size_t)m0 * CC, lane, acc);

  // epilogue: C/D layout col(N) = lane&15, row(M) = quad*4 + reg
#pragma unroll
  for (int mf = 0; mf < 2; mf++) {
#pragma unroll
    for (int r = 0; r < 4; r++) {
      int o = m0 + mf * 16 + quad * 4 + r;
      float bias = bp[o];
#pragma unroll
      for (int nf = 0; nf < 4; nf++) {
        int n = n0 + nf * 16 + lr;
        size_t idx = ((size_t)b * HIDC + o) * HW + n;
        float pre = acc[mf][nf][r] * s + bias;
        float sv  = 1.f / (1.f + expf(-pre));
        if (gate == 0) zout[idx]  = f2b(sv);
        else           rhout[idx] = f2b(sv * h[idx]);
      }
    }
  }
}

// gate q: q = tanh(pre); out = (1-z)*h + z*q
__global__ __launch_bounds__(256) void pw_q_kernel(
    const bf16*  __restrict__ dbuf,   // frag-tiled dw output, gate q
    const bf16*  __restrict__ wp,     // [128][448] int8-as-bf16
    const float* __restrict__ bp,
    const float* __restrict__ scale_p,
    const float* __restrict__ h,      // NCHW f32
    const bf16*  __restrict__ zin,    // bf16 z
    float* __restrict__ qout)
{
  int b    = blockIdx.y;
  int n0   = blockIdx.x * 64;
  int nt0  = blockIdx.x * 4;
  int wave = threadIdx.x >> 6;
  int lane = threadIdx.x & 63;
  int quad = lane >> 4;
  int lr   = lane & 15;
  int m0   = wave * 32;
  float s = *scale_p;
  f32x4 acc[2][4] = {};
  const bf16* dbt = dbuf + ((size_t)b * NT_PER_B + nt0) * (KG * 128);

  pw_gemm(dbt, wp + (size_t)m0 * CC, lane, acc);

#pragma unroll
  for (int mf = 0; mf < 2; mf++) {
#pragma unroll
    for (int r = 0; r < 4; r++) {
      int o = m0 + mf * 16 + quad * 4 + r;
      float bias = bp[o];
#pragma unroll
      for (int nf = 0; nf < 4; nf++) {
        int n = n0 + nf * 16 + lr;
        size_t idx = ((size_t)b * HIDC + o) * HW + n;
        float pre = acc[mf][nf][r] * s + bias;
        float qv = tanhf(pre);
        float zv = b2f(zin[idx]);
        float hv = h[idx];
        qout[idx] = (1.f - zv) * hv + zv * qv;
      }
    }
  }
}

extern "C" void kernel_launch(void* const* d_in, const int* in_sizes, int n_in,
                              void* d_out, int out_size, void* d_ws, size_t ws_size,
                              hipStream_t stream)
{
  const float* h   = (const float*)d_in[0];
  const float* x   = (const float*)d_in[1];
  const float* wdz = (const float*)d_in[2];
  const float* bdz = (const float*)d_in[3];
  const float* wpz = (const float*)d_in[4];
  const float* bpz = (const float*)d_in[5];
  const float* wdr = (const float*)d_in[6];
  const float* bdr = (const float*)d_in[7];
  const float* wpr = (const float*)d_in[8];
  const float* bpr = (const float*)d_in[9];
  const float* wdq = (const float*)d_in[10];
  const float* bdq = (const float*)d_in[11];
  const float* wpq = (const float*)d_in[12];
  const float* bpq = (const float*)d_in[13];

  char* ws = (char*)d_ws;
  float* qwd    = (float*)ws;                   // [0,4032) z | [4096,8128) r | [8192,12224) q
  float* scales = qwd + 12288;                  // 3 floats
  bf16*  qwp    = (bf16*)(ws + 65536);          // 3 x 57344 bf16 (int8 values)
  const size_t DBUF_ELEMS = (size_t)BB * NT_PER_B * KG * 128;  // 29,360,128
  bf16*  dz   = (bf16*)(ws + (1 << 20));                       // 58.7 MB
  bf16*  dr   = dz + DBUF_ELEMS;                               // 58.7 MB
  bf16*  zbuf = dr + DBUF_ELEMS;                               // 16.8 MB (bf16)
  bf16*  rh   = zbuf + (size_t)BB * HIDC * HW;                 // 16.8 MB

  quant_kernel<<<6, 256, 0, stream>>>(wdz, wpz, wdr, wpr, wdq, wpq, qwd, qwp, scales);

  dim3 dgrid(56, 16, 8);   // (cgroup, y-quad, batch)
  dwconv_kernel<2, float><<<dgrid, 256, 0, stream>>>(h, x, qwd, bdz, qwd + 4096, bdr, dz, dr);

  dim3 zrgrid(128, 8, 2);  // (64-wide n-tile, batch, gate z/r)
  pw_zr_kernel<<<zrgrid, 256, 0, stream>>>(dz, dr, qwp, bpz, bpr, scales, h, zbuf, rh);

  dwconv_kernel<1, bf16><<<dgrid, 256, 0, stream>>>(rh, x, qwd + 8192, bdq, nullptr, nullptr,
                                                    dz, nullptr);

  dim3 pgrid(128, 8);      // (64-wide n-tile, batch)
  pw_q_kernel<<<pgrid, 256, 0, stream>>>(dz, qwp + 2 * HIDC * CC, bpq, scales + 2, h, zbuf,
                                         (float*)d_out);
}